// Round 6
// baseline (657.433 us; speedup 1.0000x reference)
//
#include <hip/hip_runtime.h>
#include <stdint.h>
#include <math.h>

typedef unsigned short u16;
typedef __attribute__((ext_vector_type(8))) __bf16 v8bf;
typedef v8bf __attribute__((may_alias)) v8bf_a;
typedef __attribute__((ext_vector_type(4))) float v4f;
typedef __attribute__((ext_vector_type(4))) u16 v4u16;
typedef v4u16 __attribute__((may_alias)) v4u16_a;
typedef __attribute__((ext_vector_type(8))) u16 v8u16;
typedef v8u16 __attribute__((may_alias)) v8u16_a;

__device__ __forceinline__ float bf2f(u16 u) {
    union { uint32_t i; float f; } c; c.i = ((uint32_t)u) << 16; return c.f;
}
__device__ __forceinline__ u16 f2bf(float f) {
    union { float f; uint32_t i; } c; c.f = f;
    return (u16)((c.i + 0x7FFFu + ((c.i >> 16) & 1u)) >> 16);
}
__device__ __forceinline__ void gl_lds16(const u16* g, u16* l) {
    __builtin_amdgcn_global_load_lds(
        (const __attribute__((address_space(1))) void*)g,
        (__attribute__((address_space(3))) void*)l, 16, 0, 0);
}

// ---------------------------------------------------------------------------
// fp32 -> bf16 conversion (inputs are fp32: proven by round-2/3 NaN bisect).
// ---------------------------------------------------------------------------
__global__ __launch_bounds__(256) void convert_bf16(
    const float* __restrict__ src, u16* __restrict__ dst, int n)
{
    const int stride = gridDim.x * blockDim.x;
    for (int i = blockIdx.x * blockDim.x + threadIdx.x; i * 8 < n; i += stride) {
        const int base = i * 8;
        v8u16 o;
#pragma unroll
        for (int j = 0; j < 8; j++) o[j] = f2bf(src[base + j]);
        *(v8u16_a*)(dst + base) = o;
    }
}

// ---------------------------------------------------------------------------
// B^T GEMM: C[m][n] = sum_k A[m][k] * W[n][k].  m97-style 128x128 tile, BK=32.
// ---------------------------------------------------------------------------
template <bool F32OUT>
__global__ __launch_bounds__(256) void gemm_bt(
    const u16* __restrict__ A, int lda,
    const u16* __restrict__ W0, const u16* __restrict__ W1, const u16* __restrict__ W2,
    int n1, int n2, void* __restrict__ Cv, int ldc, int K)
{
    __shared__ __align__(16) u16 As[128 * 32];
    __shared__ __align__(16) u16 Bs[128 * 32];
    const int t  = threadIdx.x;
    const int m0 = blockIdx.x * 128, n0 = blockIdx.y * 128;

    const u16* W; int nw;
    if (n0 < n1)      { W = W0; nw = n0; }
    else if (n0 < n2) { W = W1; nw = n0 - n1; }
    else              { W = W2; nw = n0 - n2; }

    const int lrow = t >> 2, lcol = (t & 3) * 8;
    const u16* gA = A + (size_t)(m0 + lrow) * lda + lcol;
    const u16* gB = W + (size_t)(nw + lrow) * K + lcol;

    const int wid = t >> 6, lane = t & 63;
    const int wm = (wid >> 1) * 64, wn = (wid & 1) * 64;
    const int l15 = lane & 15, quad = lane >> 4;

    v4f acc[4][4] = {};

    for (int k0 = 0; k0 < K; k0 += 32) {
        gl_lds16(gA + k0,                      As + t * 8);
        gl_lds16(gA + k0 + (size_t)64 * lda,   As + 2048 + t * 8);
        gl_lds16(gB + k0,                      Bs + t * 8);
        gl_lds16(gB + k0 + (size_t)64 * K,     Bs + 2048 + t * 8);
        __syncthreads();
        v8bf af[4], bfr[4];
#pragma unroll
        for (int i = 0; i < 4; i++) af[i]  = *(const v8bf_a*)(As + (wm + i * 16 + l15) * 32 + quad * 8);
#pragma unroll
        for (int j = 0; j < 4; j++) bfr[j] = *(const v8bf_a*)(Bs + (wn + j * 16 + l15) * 32 + quad * 8);
#pragma unroll
        for (int i = 0; i < 4; i++)
#pragma unroll
            for (int j = 0; j < 4; j++)
                acc[i][j] = __builtin_amdgcn_mfma_f32_16x16x32_bf16(af[i], bfr[j], acc[i][j], 0, 0, 0);
        __syncthreads();
    }

#pragma unroll
    for (int i = 0; i < 4; i++)
#pragma unroll
        for (int j = 0; j < 4; j++)
#pragma unroll
            for (int r = 0; r < 4; r++) {
                const int row = m0 + wm + i * 16 + quad * 4 + r;
                const int col = n0 + wn + j * 16 + l15;
                if (F32OUT) ((float*)Cv)[(size_t)row * ldc + col] = acc[i][j][r];
                else        ((u16*)Cv)[(size_t)row * ldc + col]   = f2bf(acc[i][j][r]);
            }
}

// ---------------------------------------------------------------------------
// RMSNorm + RoPE on q (16 heads) and k (8 heads), IN-PLACE on qkv.
// ---------------------------------------------------------------------------
__global__ __launch_bounds__(256) void normrope(
    u16* __restrict__ qkv, const u16* __restrict__ qw, const u16* __restrict__ kw)
{
    const int tok = blockIdx.x;
    const int s = tok & 2047;
    const int wid = threadIdx.x >> 6, lane = threadIdx.x & 63;
    const int d  = lane * 2;
    const int dm = d & 63;
    const float kln = 9.210340371976184f / 64.f;
    const float inv0 = expf(-(float)dm * kln);
    const float inv1 = expf(-(float)(dm + 1) * kln);
    float sn0, cs0, sn1, cs1;
    __sincosf((float)s * inv0, &sn0, &cs0);
    __sincosf((float)s * inv1, &sn1, &cs1);

    for (int task = wid; task < 24; task += 4) {
        const bool isq = task < 16;
        const int  hh  = isq ? task : task - 16;
        u16* p = qkv + (size_t)tok * 4096 + (isq ? hh * 128 : 2048 + hh * 128) + d;
        const float x0 = bf2f(p[0]), x1 = bf2f(p[1]);
        float ss = x0 * x0 + x1 * x1;
#pragma unroll
        for (int off = 32; off; off >>= 1) ss += __shfl_xor(ss, off);
        const float rr = rsqrtf(ss * (1.f / 128.f) + 1e-6f);
        const u16* wp = (isq ? qw : kw) + d;
        const float xn0 = x0 * rr * (1.f + bf2f(wp[0]));
        const float xn1 = x1 * rr * (1.f + bf2f(wp[1]));
        const float pp0 = __shfl_xor(xn0, 32);
        const float pp1 = __shfl_xor(xn1, 32);
        float o0, o1;
        if (lane < 32) { o0 = xn0 * cs0 - pp0 * sn0; o1 = xn1 * cs1 - pp1 * sn1; }
        else           { o0 = xn0 * cs0 + pp0 * sn0; o1 = xn1 * cs1 + pp1 * sn1; }
        p[0] = f2bf(o0); p[1] = f2bf(o1);
    }
}

// ---------------------------------------------------------------------------
// V transpose: qkv v-cols [tok][3072 + c]  ->  v_t[b*1024 + c][s]
// ---------------------------------------------------------------------------
__global__ __launch_bounds__(256) void vtrans(
    const u16* __restrict__ qkv, u16* __restrict__ v_t)
{
    __shared__ __align__(16) u16 tile[64][80];
    const int b = blockIdx.x, st = blockIdx.y * 64, ct = blockIdx.z * 64;
    const int t = threadIdx.x;
    {
        const int sl = t >> 2, cq = (t & 3) * 16;
        const u16* src = qkv + ((size_t)(b * 2048 + st + sl)) * 4096 + 3072 + ct + cq;
        *(v8u16_a*)&tile[sl][cq]     = *(const v8u16_a*)src;
        *(v8u16_a*)&tile[sl][cq + 8] = *(const v8u16_a*)(src + 8);
    }
    __syncthreads();
    {
        const int dl = t >> 2, sq = (t & 3) * 16;
        v8u16 o0, o1;
#pragma unroll
        for (int i = 0; i < 8; i++) { o0[i] = tile[sq + i][dl]; o1[i] = tile[sq + 8 + i][dl]; }
        u16* dst = v_t + ((size_t)(b * 1024 + ct + dl)) * 2048 + st + sq;
        *(v8u16_a*)dst       = o0;
        *(v8u16_a*)(dst + 8) = o1;
    }
}

// ---------------------------------------------------------------------------
// Flash attention, sliding window 1024, GQA groups=2. One wave = 16 queries.
// ALL-REGISTER pipeline: S^T via mfma(K,Q) (query=lane&15); P stays in regs —
// PV uses key-permutation sigma(8q+j)=4q+(j&3)+16*(j>>2), which makes the
// natural p[0..7] register order a valid B-fragment and V^T the A-fragment
// (two 8B loads per nt). K register-double-buffered one tile ahead; V issued
// at iteration top. No LDS, no barriers.
// ---------------------------------------------------------------------------
__global__ __launch_bounds__(256) void attn_fa(
    const u16* __restrict__ qkv,   // [tok][4096]
    const u16* __restrict__ v_t,   // [b*1024 + kvh*128+d][2048]
    u16* __restrict__ attn)        // [tok][h*128+d]
{
    const int bh = blockIdx.y;          // head (swapped for load balance)
    const int b = bh >> 4, h = bh & 15, kvh = h >> 1;
    const int wid = threadIdx.x >> 6, lane = threadIdx.x & 63;
    const int l15 = lane & 15, quad = lane >> 4;
    const int qw0 = blockIdx.x * 64 + wid * 16;
    const int q   = qw0 + l15;

    const u16* Qb = qkv + ((size_t)(b * 2048 + q)) * 4096 + h * 128 + quad * 8;
    v8bf qf[4];
#pragma unroll
    for (int kc = 0; kc < 4; kc++) qf[kc] = *(const v8bf_a*)(Qb + kc * 32);

    const u16* Kb = qkv + (size_t)b * 2048 * 4096 + 2048 + kvh * 128;
    const u16* Vb = v_t + (size_t)(b * 1024 + kvh * 128) * 2048;

    v4f o[8] = {};             // O^T: d = nt*16 + quad*4 + r, query = l15
    float m_i = -INFINITY, l_i = 0.f;

    int ks = qw0 - 1023; if (ks < 0) ks = 0;
    const int kstart = ks & ~31, kend = qw0 + 15;
    const float scale = 0.08838834764831845f;  // 1/sqrt(128)

    // preload K fragments for the first tile
    v8bf k0[4], k1[4];
    {
        const u16* Kr0 = Kb + (size_t)(kstart + l15) * 4096 + quad * 8;
        const u16* Kr1 = Kr0 + (size_t)16 * 4096;
#pragma unroll
        for (int kc = 0; kc < 4; kc++) {
            k0[kc] = *(const v8bf_a*)(Kr0 + kc * 32);
            k1[kc] = *(const v8bf_a*)(Kr1 + kc * 32);
        }
    }

    for (int kt = kstart; kt <= kend; kt += 32) {
        // prefetch K for tile kt+32 (rows clamped in-bounds; unused at tail)
        v8bf kn0[4], kn1[4];
        {
            int r0 = kt + 32 + l15; if (r0 > 2047) r0 = 2047;
            int r1 = kt + 48 + l15; if (r1 > 2047) r1 = 2047;
            const u16* Kr0 = Kb + (size_t)r0 * 4096 + quad * 8;
            const u16* Kr1 = Kb + (size_t)r1 * 4096 + quad * 8;
#pragma unroll
            for (int kc = 0; kc < 4; kc++) {
                kn0[kc] = *(const v8bf_a*)(Kr0 + kc * 32);
                kn1[kc] = *(const v8bf_a*)(Kr1 + kc * 32);
            }
        }
        // V fragments for current tile (sigma order: two 8B halves per nt)
        v8u16 vf[8];
#pragma unroll
        for (int nt = 0; nt < 8; nt++) {
            const u16* va = Vb + (size_t)(nt * 16 + l15) * 2048 + kt + quad * 4;
            const v4u16 lo = *(const v4u16_a*)va;
            const v4u16 hi = *(const v4u16_a*)(va + 16);
            vf[nt] = (v8u16){lo[0], lo[1], lo[2], lo[3], hi[0], hi[1], hi[2], hi[3]};
        }

        v4f s0 = {}, s1 = {};
#pragma unroll
        for (int kc = 0; kc < 4; kc++) {
            s0 = __builtin_amdgcn_mfma_f32_16x16x32_bf16(k0[kc], qf[kc], s0, 0, 0, 0);
            s1 = __builtin_amdgcn_mfma_f32_16x16x32_bf16(k1[kc], qf[kc], s1, 0, 0, 0);
        }

        // mask + scale; this lane's keys: kt+quad*4+r (s0), +16 (s1)
        float p[8];
        float mx = -INFINITY;
#pragma unroll
        for (int r = 0; r < 4; r++) {
            const int kk0 = kt + quad * 4 + r, kk1 = kk0 + 16;
            const float v0 = (kk0 <= q && kk0 > q - 1024) ? s0[r] * scale : -INFINITY;
            const float v1 = (kk1 <= q && kk1 > q - 1024) ? s1[r] * scale : -INFINITY;
            p[r] = v0; p[r + 4] = v1;
            mx = fmaxf(mx, fmaxf(v0, v1));
        }
        mx = fmaxf(mx, __shfl_xor(mx, 16));
        mx = fmaxf(mx, __shfl_xor(mx, 32));
        const float mnew  = fmaxf(m_i, mx);
        const float msafe = (mnew == -INFINITY) ? 0.f : mnew;
        const float alpha = __expf(m_i - msafe);
        m_i = mnew;
        float ps = 0.f;
#pragma unroll
        for (int j = 0; j < 8; j++) { p[j] = __expf(p[j] - msafe); ps += p[j]; }
        ps += __shfl_xor(ps, 16);
        ps += __shfl_xor(ps, 32);
        l_i = l_i * alpha + ps;

        // pack P as bf16 B-fragment (natural register order == sigma order)
        union { v8u16 u; v8bf b; } pc;
#pragma unroll
        for (int j = 0; j < 8; j++) pc.u[j] = f2bf(p[j]);

#pragma unroll
        for (int nt = 0; nt < 8; nt++)
#pragma unroll
            for (int r = 0; r < 4; r++) o[nt][r] *= alpha;

#pragma unroll
        for (int nt = 0; nt < 8; nt++) {
            union { v8u16 u; v8bf b; } vc; vc.u = vf[nt];
            o[nt] = __builtin_amdgcn_mfma_f32_16x16x32_bf16(vc.b, pc.b, o[nt], 0, 0, 0);
        }

#pragma unroll
        for (int kc = 0; kc < 4; kc++) { k0[kc] = kn0[kc]; k1[kc] = kn1[kc]; }
    }

    const float inv = 1.0f / l_i;
    u16* orow = attn + ((size_t)(b * 2048 + q)) * 2048 + h * 128 + quad * 4;
#pragma unroll
    for (int nt = 0; nt < 8; nt++) {
        v4u16 ov;
#pragma unroll
        for (int r = 0; r < 4; r++) ov[r] = f2bf(o[nt][r] * inv);
        *(v4u16_a*)(orow + nt * 16) = ov;
    }
}

// ---------------------------------------------------------------------------
extern "C" void kernel_launch(void* const* d_in, const int* in_sizes, int n_in,
                              void* d_out, int out_size, void* d_ws, size_t ws_size,
                              hipStream_t stream)
{
    // workspace layout (u16 elements)
    u16* qkv  = (u16*)d_ws;                            // [4096][4096]
    u16* v_t  = qkv  + (size_t)16777216;               // [2048][2048]
    u16* xa   = v_t  + (size_t)4194304;                // x_bf16, later attn
    u16* wbf  = xa   + (size_t)8388608;                // wq|wk|wv, later wo
    u16* nwq  = wbf  + (size_t)8388608;                // 128
    u16* nwk  = nwq  + 128;                            // 128

    // 0) materialize bf16 copies of fp32 inputs
    convert_bf16<<<4096, 256, 0, stream>>>((const float*)d_in[0], xa,            8388608); // x
    convert_bf16<<<2048, 256, 0, stream>>>((const float*)d_in[1], wbf,           4194304); // wq
    convert_bf16<<<1024, 256, 0, stream>>>((const float*)d_in[2], wbf + 4194304, 2097152); // wk
    convert_bf16<<<1024, 256, 0, stream>>>((const float*)d_in[3], wbf + 6291456, 2097152); // wv
    convert_bf16<<<1,    256, 0, stream>>>((const float*)d_in[5], nwq,           128);     // q_norm
    convert_bf16<<<1,    256, 0, stream>>>((const float*)d_in[6], nwk,           128);     // k_norm
    // 1) fused QKV projection
    gemm_bt<false><<<dim3(32, 32), 256, 0, stream>>>(xa, 2048, wbf, wbf + 4194304, wbf + 6291456,
                                                     2048, 3072, qkv, 4096, 2048);
    // 2) wo -> bf16, overwriting the now-dead wq slot
    convert_bf16<<<2048, 256, 0, stream>>>((const float*)d_in[4], wbf, 4194304);
    // 3) RMSNorm + RoPE for q,k (in-place)
    normrope<<<dim3(4096), 256, 0, stream>>>(qkv, nwq, nwk);
    // 4) V transpose for PV A-operand
    vtrans<<<dim3(2, 32, 16), 256, 0, stream>>>(qkv, v_t);
    // 5) sliding-window flash attention (attn overwrites dead x_bf16)
    attn_fa<<<dim3(32, 32), 256, 0, stream>>>(qkv, v_t, xa);
    // 6) output projection -> d_out as FP32 (reference output dtype)
    gemm_bt<true><<<dim3(32, 16), 256, 0, stream>>>(xa, 2048, wbf, wbf, wbf,
                                                    2048, 4096, d_out, 2048, 2048);
}

// Round 7
// 431.325 us; speedup vs baseline: 1.5242x; 1.5242x over previous
//
#include <hip/hip_runtime.h>
#include <stdint.h>
#include <math.h>

typedef unsigned short u16;
typedef __attribute__((ext_vector_type(8))) __bf16 v8bf;
typedef v8bf __attribute__((may_alias)) v8bf_a;
typedef __attribute__((ext_vector_type(4))) float v4f;
typedef __attribute__((ext_vector_type(4))) u16 v4u16;
typedef v4u16 __attribute__((may_alias)) v4u16_a;
typedef __attribute__((ext_vector_type(8))) u16 v8u16;
typedef v8u16 __attribute__((may_alias)) v8u16_a;

__device__ __forceinline__ float bf2f(u16 u) {
    union { uint32_t i; float f; } c; c.i = ((uint32_t)u) << 16; return c.f;
}
__device__ __forceinline__ u16 f2bf(float f) {
    union { float f; uint32_t i; } c; c.f = f;
    return (u16)((c.i + 0x7FFFu + ((c.i >> 16) & 1u)) >> 16);
}
__device__ __forceinline__ void gl_lds16(const u16* g, u16* l) {
    __builtin_amdgcn_global_load_lds(
        (const __attribute__((address_space(1))) void*)g,
        (__attribute__((address_space(3))) void*)l, 16, 0, 0);
}

// ---------------------------------------------------------------------------
// fp32 -> bf16 conversion (inputs are fp32: proven by round-2/3 NaN bisect).
// ---------------------------------------------------------------------------
__global__ __launch_bounds__(256) void convert_bf16(
    const float* __restrict__ src, u16* __restrict__ dst, int n)
{
    const int stride = gridDim.x * blockDim.x;
    for (int i = blockIdx.x * blockDim.x + threadIdx.x; i * 8 < n; i += stride) {
        const int base = i * 8;
        v8u16 o;
#pragma unroll
        for (int j = 0; j < 8; j++) o[j] = f2bf(src[base + j]);
        *(v8u16_a*)(dst + base) = o;
    }
}

// ---------------------------------------------------------------------------
// B^T GEMM: C[m][n] = sum_k A[m][k] * W[n][k].  m97-style 128x128 tile, BK=32.
// ---------------------------------------------------------------------------
template <bool F32OUT>
__global__ __launch_bounds__(256) void gemm_bt(
    const u16* __restrict__ A, int lda,
    const u16* __restrict__ W0, const u16* __restrict__ W1, const u16* __restrict__ W2,
    int n1, int n2, void* __restrict__ Cv, int ldc, int K)
{
    __shared__ __align__(16) u16 As[128 * 32];
    __shared__ __align__(16) u16 Bs[128 * 32];
    const int t  = threadIdx.x;
    const int m0 = blockIdx.x * 128, n0 = blockIdx.y * 128;

    const u16* W; int nw;
    if (n0 < n1)      { W = W0; nw = n0; }
    else if (n0 < n2) { W = W1; nw = n0 - n1; }
    else              { W = W2; nw = n0 - n2; }

    const int lrow = t >> 2, lcol = (t & 3) * 8;
    const u16* gA = A + (size_t)(m0 + lrow) * lda + lcol;
    const u16* gB = W + (size_t)(nw + lrow) * K + lcol;

    const int wid = t >> 6, lane = t & 63;
    const int wm = (wid >> 1) * 64, wn = (wid & 1) * 64;
    const int l15 = lane & 15, quad = lane >> 4;

    v4f acc[4][4] = {};

    for (int k0 = 0; k0 < K; k0 += 32) {
        gl_lds16(gA + k0,                      As + t * 8);
        gl_lds16(gA + k0 + (size_t)64 * lda,   As + 2048 + t * 8);
        gl_lds16(gB + k0,                      Bs + t * 8);
        gl_lds16(gB + k0 + (size_t)64 * K,     Bs + 2048 + t * 8);
        __syncthreads();
        v8bf af[4], bfr[4];
#pragma unroll
        for (int i = 0; i < 4; i++) af[i]  = *(const v8bf_a*)(As + (wm + i * 16 + l15) * 32 + quad * 8);
#pragma unroll
        for (int j = 0; j < 4; j++) bfr[j] = *(const v8bf_a*)(Bs + (wn + j * 16 + l15) * 32 + quad * 8);
#pragma unroll
        for (int i = 0; i < 4; i++)
#pragma unroll
            for (int j = 0; j < 4; j++)
                acc[i][j] = __builtin_amdgcn_mfma_f32_16x16x32_bf16(af[i], bfr[j], acc[i][j], 0, 0, 0);
        __syncthreads();
    }

#pragma unroll
    for (int i = 0; i < 4; i++)
#pragma unroll
        for (int j = 0; j < 4; j++)
#pragma unroll
            for (int r = 0; r < 4; r++) {
                const int row = m0 + wm + i * 16 + quad * 4 + r;
                const int col = n0 + wn + j * 16 + l15;
                if (F32OUT) ((float*)Cv)[(size_t)row * ldc + col] = acc[i][j][r];
                else        ((u16*)Cv)[(size_t)row * ldc + col]   = f2bf(acc[i][j][r]);
            }
}

// ---------------------------------------------------------------------------
// RMSNorm + RoPE on q (16 heads) and k (8 heads), IN-PLACE on qkv.
// ---------------------------------------------------------------------------
__global__ __launch_bounds__(256) void normrope(
    u16* __restrict__ qkv, const u16* __restrict__ qw, const u16* __restrict__ kw)
{
    const int tok = blockIdx.x;
    const int s = tok & 2047;
    const int wid = threadIdx.x >> 6, lane = threadIdx.x & 63;
    const int d  = lane * 2;
    const int dm = d & 63;
    const float kln = 9.210340371976184f / 64.f;
    const float inv0 = expf(-(float)dm * kln);
    const float inv1 = expf(-(float)(dm + 1) * kln);
    float sn0, cs0, sn1, cs1;
    __sincosf((float)s * inv0, &sn0, &cs0);
    __sincosf((float)s * inv1, &sn1, &cs1);

    for (int task = wid; task < 24; task += 4) {
        const bool isq = task < 16;
        const int  hh  = isq ? task : task - 16;
        u16* p = qkv + (size_t)tok * 4096 + (isq ? hh * 128 : 2048 + hh * 128) + d;
        const float x0 = bf2f(p[0]), x1 = bf2f(p[1]);
        float ss = x0 * x0 + x1 * x1;
#pragma unroll
        for (int off = 32; off; off >>= 1) ss += __shfl_xor(ss, off);
        const float rr = rsqrtf(ss * (1.f / 128.f) + 1e-6f);
        const u16* wp = (isq ? qw : kw) + d;
        const float xn0 = x0 * rr * (1.f + bf2f(wp[0]));
        const float xn1 = x1 * rr * (1.f + bf2f(wp[1]));
        const float pp0 = __shfl_xor(xn0, 32);
        const float pp1 = __shfl_xor(xn1, 32);
        float o0, o1;
        if (lane < 32) { o0 = xn0 * cs0 - pp0 * sn0; o1 = xn1 * cs1 - pp1 * sn1; }
        else           { o0 = xn0 * cs0 + pp0 * sn0; o1 = xn1 * cs1 + pp1 * sn1; }
        p[0] = f2bf(o0); p[1] = f2bf(o1);
    }
}

// ---------------------------------------------------------------------------
// V transpose: qkv v-cols [tok][3072 + c]  ->  v_t[b*1024 + c][s]
// ---------------------------------------------------------------------------
__global__ __launch_bounds__(256) void vtrans(
    const u16* __restrict__ qkv, u16* __restrict__ v_t)
{
    __shared__ __align__(16) u16 tile[64][80];
    const int b = blockIdx.x, st = blockIdx.y * 64, ct = blockIdx.z * 64;
    const int t = threadIdx.x;
    {
        const int sl = t >> 2, cq = (t & 3) * 16;
        const u16* src = qkv + ((size_t)(b * 2048 + st + sl)) * 4096 + 3072 + ct + cq;
        *(v8u16_a*)&tile[sl][cq]     = *(const v8u16_a*)src;
        *(v8u16_a*)&tile[sl][cq + 8] = *(const v8u16_a*)(src + 8);
    }
    __syncthreads();
    {
        const int dl = t >> 2, sq = (t & 3) * 16;
        v8u16 o0, o1;
#pragma unroll
        for (int i = 0; i < 8; i++) { o0[i] = tile[sq + i][dl]; o1[i] = tile[sq + 8 + i][dl]; }
        u16* dst = v_t + ((size_t)(b * 1024 + ct + dl)) * 2048 + st + sq;
        *(v8u16_a*)dst       = o0;
        *(v8u16_a*)(dst + 8) = o1;
    }
}

// ---------------------------------------------------------------------------
// Flash attention, sliding window 1024, GQA groups=2. Block = 64 queries x 1
// head (4 waves x 16 q). K tiles (32x128) staged cooperatively into LDS via
// global_load_lds (16B, XOR-swizzled 16B chunks: c^(row&7) -> 2-way banks),
// double-buffered, one __syncthreads per tile. V loaded from v_t (16B lanes)
// at iteration top so latency overlaps QK+softmax. P via per-wave LDS tile.
// ---------------------------------------------------------------------------
__global__ __launch_bounds__(256) void attn_fa(
    const u16* __restrict__ qkv,   // [tok][4096]
    const u16* __restrict__ v_t,   // [b*1024 + kvh*128+d][2048]
    u16* __restrict__ attn)        // [tok][h*128+d]
{
    __shared__ __align__(16) u16 Ks[2][32 * 128];
    __shared__ __align__(16) u16 p_lds[4][16 * 48];
    const int bh = blockIdx.x;
    const int b = bh >> 4, h = bh & 15, kvh = h >> 1;
    const int t = threadIdx.x;
    const int wid = t >> 6, lane = t & 63;
    const int l15 = lane & 15, quad = lane >> 4;
    const int qb0 = blockIdx.y * 64;
    const int qw0 = qb0 + wid * 16;
    const int q   = qw0 + l15;

    const u16* Qb = qkv + ((size_t)(b * 2048 + q)) * 4096 + h * 128 + quad * 8;
    v8bf qf[4];
#pragma unroll
    for (int kc = 0; kc < 4; kc++) qf[kc] = *(const v8bf_a*)(Qb + kc * 32);

    const u16* Kb = qkv + (size_t)b * 2048 * 4096 + 2048 + kvh * 128;
    const u16* Vb = v_t + (size_t)(b * 1024 + kvh * 128) * 2048;

    // block-uniform K range
    int ks = qb0 - 1023; if (ks < 0) ks = 0;
    const int kstart = ks & ~31, kend = qb0 + 63;

    // staging map: thread t covers (row, chunk16) = (t>>4, t&15) and (+16, same)
    const int sr0 = t >> 4, sc = t & 15, sr1 = sr0 + 16;
    const int so0 = (sc ^ (sr0 & 7)) * 8;   // swizzled source col (u16)
    const int so1 = (sc ^ (sr1 & 7)) * 8;

    gl_lds16(Kb + (size_t)(kstart + sr0) * 4096 + so0, &Ks[0][(size_t)t * 8]);
    gl_lds16(Kb + (size_t)(kstart + sr1) * 4096 + so1, &Ks[0][(size_t)(256 + t) * 8]);

    v4f o[8] = {};             // O^T: d = nt*16 + quad*4 + r, query = l15
    float m_i = -INFINITY, l_i = 0.f;
    const float scale = 0.08838834764831845f;  // 1/sqrt(128)
    u16* P = &p_lds[wid][0];
    const int swz = l15 & 7;

    int buf = 0;
    for (int kt = kstart; kt <= kend; kt += 32, buf ^= 1) {
        __syncthreads();   // staging of `buf` complete; prior reads of buf^1 done
        if (kt + 32 <= kend) {
            gl_lds16(Kb + (size_t)(kt + 32 + sr0) * 4096 + so0, &Ks[buf ^ 1][(size_t)t * 8]);
            gl_lds16(Kb + (size_t)(kt + 32 + sr1) * 4096 + so1, &Ks[buf ^ 1][(size_t)(256 + t) * 8]);
        }
        // V fragments: issue early, overlap with QK + softmax
        v8bf vf[8];
        const u16* Vr = Vb + (size_t)l15 * 2048 + kt + quad * 8;
#pragma unroll
        for (int nt = 0; nt < 8; nt++) vf[nt] = *(const v8bf_a*)(Vr + (size_t)nt * 16 * 2048);

        // QK from swizzled LDS: rows l15 / l15+16, d-chunk (kc*4+quad)^swz
        v4f s0 = {}, s1 = {};
        const u16* K0 = &Ks[buf][(size_t)l15 * 128];
        const u16* K1 = K0 + 16 * 128;
#pragma unroll
        for (int kc = 0; kc < 4; kc++) {
            const int cs = ((kc * 4 + quad) ^ swz) * 8;
            s0 = __builtin_amdgcn_mfma_f32_16x16x32_bf16(*(const v8bf_a*)(K0 + cs), qf[kc], s0, 0, 0, 0);
            s1 = __builtin_amdgcn_mfma_f32_16x16x32_bf16(*(const v8bf_a*)(K1 + cs), qf[kc], s1, 0, 0, 0);
        }

        // mask + scale; this lane's keys: kt+quad*4+r (s0), +16 (s1)
        float p[8];
        float mx = -INFINITY;
#pragma unroll
        for (int r = 0; r < 4; r++) {
            const int kk0 = kt + quad * 4 + r, kk1 = kk0 + 16;
            const float v0 = (kk0 <= q && kk0 > q - 1024) ? s0[r] * scale : -INFINITY;
            const float v1 = (kk1 <= q && kk1 > q - 1024) ? s1[r] * scale : -INFINITY;
            p[r] = v0; p[r + 4] = v1;
            mx = fmaxf(mx, fmaxf(v0, v1));
        }
        mx = fmaxf(mx, __shfl_xor(mx, 16));
        mx = fmaxf(mx, __shfl_xor(mx, 32));
        const float mnew  = fmaxf(m_i, mx);
        const float msafe = (mnew == -INFINITY) ? 0.f : mnew;
        const float alpha = __expf(m_i - msafe);
        m_i = mnew;
        float ps = 0.f;
#pragma unroll
        for (int j = 0; j < 8; j++) { p[j] = __expf(p[j] - msafe); ps += p[j]; }
        ps += __shfl_xor(ps, 16);
        ps += __shfl_xor(ps, 32);
        l_i = l_i * alpha + ps;

        // P^T -> per-wave LDS: row = query l15 (stride 48), col = key-in-tile
        v4u16 pk0, pk1;
#pragma unroll
        for (int r = 0; r < 4; r++) { pk0[r] = f2bf(p[r]); pk1[r] = f2bf(p[r + 4]); }
        *(v4u16_a*)(P + l15 * 48 + quad * 4)      = pk0;
        *(v4u16_a*)(P + l15 * 48 + 16 + quad * 4) = pk1;

#pragma unroll
        for (int nt = 0; nt < 8; nt++)
#pragma unroll
            for (int r = 0; r < 4; r++) o[nt][r] *= alpha;

        asm volatile("s_waitcnt lgkmcnt(0)" ::: "memory");
        const v8bf pf = *(const v8bf_a*)(P + l15 * 48 + quad * 8);  // B-frag of P^T
#pragma unroll
        for (int nt = 0; nt < 8; nt++)
            o[nt] = __builtin_amdgcn_mfma_f32_16x16x32_bf16(vf[nt], pf, o[nt], 0, 0, 0);
    }

    const float inv = 1.0f / l_i;
    u16* orow = attn + ((size_t)(b * 2048 + q)) * 2048 + h * 128 + quad * 4;
#pragma unroll
    for (int nt = 0; nt < 8; nt++) {
        v4u16 ov;
#pragma unroll
        for (int r = 0; r < 4; r++) ov[r] = f2bf(o[nt][r] * inv);
        *(v4u16_a*)(orow + nt * 16) = ov;
    }
}

// ---------------------------------------------------------------------------
extern "C" void kernel_launch(void* const* d_in, const int* in_sizes, int n_in,
                              void* d_out, int out_size, void* d_ws, size_t ws_size,
                              hipStream_t stream)
{
    // workspace layout (u16 elements)
    u16* qkv  = (u16*)d_ws;                            // [4096][4096]
    u16* v_t  = qkv  + (size_t)16777216;               // [2048][2048]
    u16* xa   = v_t  + (size_t)4194304;                // x_bf16, later attn
    u16* wbf  = xa   + (size_t)8388608;                // wq|wk|wv, later wo
    u16* nwq  = wbf  + (size_t)8388608;                // 128
    u16* nwk  = nwq  + 128;                            // 128

    // 0) materialize bf16 copies of fp32 inputs
    convert_bf16<<<4096, 256, 0, stream>>>((const float*)d_in[0], xa,            8388608); // x
    convert_bf16<<<2048, 256, 0, stream>>>((const float*)d_in[1], wbf,           4194304); // wq
    convert_bf16<<<1024, 256, 0, stream>>>((const float*)d_in[2], wbf + 4194304, 2097152); // wk
    convert_bf16<<<1024, 256, 0, stream>>>((const float*)d_in[3], wbf + 6291456, 2097152); // wv
    convert_bf16<<<1,    256, 0, stream>>>((const float*)d_in[5], nwq,           128);     // q_norm
    convert_bf16<<<1,    256, 0, stream>>>((const float*)d_in[6], nwk,           128);     // k_norm
    // 1) fused QKV projection
    gemm_bt<false><<<dim3(32, 32), 256, 0, stream>>>(xa, 2048, wbf, wbf + 4194304, wbf + 6291456,
                                                     2048, 3072, qkv, 4096, 2048);
    // 2) wo -> bf16, overwriting the now-dead wq slot
    convert_bf16<<<2048, 256, 0, stream>>>((const float*)d_in[4], wbf, 4194304);
    // 3) RMSNorm + RoPE for q,k (in-place)
    normrope<<<dim3(4096), 256, 0, stream>>>(qkv, nwq, nwk);
    // 4) V transpose for PV A-operand
    vtrans<<<dim3(2, 32, 16), 256, 0, stream>>>(qkv, v_t);
    // 5) sliding-window flash attention (attn overwrites dead x_bf16)
    attn_fa<<<dim3(32, 32), 256, 0, stream>>>(qkv, v_t, xa);
    // 6) output projection -> d_out as FP32 (reference output dtype)
    gemm_bt<true><<<dim3(32, 16), 256, 0, stream>>>(xa, 2048, wbf, wbf, wbf,
                                                    2048, 4096, d_out, 2048, 2048);
}